// Round 2
// baseline (1584.104 us; speedup 1.0000x reference)
//
#include <hip/hip_runtime.h>

static inline int idiv_up(int a, int b) { return (a + b - 1) / b; }

// ---------------- degree / norm ----------------
__global__ __launch_bounds__(256) void k_deg(const int* __restrict__ dst, int E,
                                             float* __restrict__ deg) {
    int i = blockIdx.x * 256 + threadIdx.x;
    if (i < E) atomicAdd(&deg[dst[i]], 1.0f);
}

__global__ __launch_bounds__(256) void k_dinv(const float* __restrict__ deg,
                                              float* __restrict__ dinv, int N) {
    int i = blockIdx.x * 256 + threadIdx.x;
    if (i < N) dinv[i] = rsqrtf(deg[i] + 1.0f);  // +1 = self loop
}

// ---------------- fp32 GEMM: C[N,128] = A[N,128] @ W[128,128] ----------------
// 64x64 tile per block, 256 threads, 4x4 outputs per thread.
__global__ __launch_bounds__(256) void k_gemm(const float* __restrict__ A,
                                              const float* __restrict__ W,
                                              float* __restrict__ C, int N) {
    __shared__ float Xt[128][64];  // A tile transposed: Xt[k][r]
    __shared__ float Ws[128][64];  // W tile: Ws[k][c]
    const int t = threadIdx.x;
    const int row0 = blockIdx.x * 64;
    const int col0 = blockIdx.y * 64;

    // stage A tile (64 rows x 128 k), transposed into LDS
    {
        const int r  = t >> 2;
        const int c0 = (t & 3) * 32;
        const int row = row0 + r;
        const float* src = A + (size_t)row * 128 + c0;
#pragma unroll
        for (int j = 0; j < 8; ++j) {
            float4 v = make_float4(0.f, 0.f, 0.f, 0.f);
            if (row < N) v = *(const float4*)(src + j * 4);
            const int c = c0 + j * 4;
            Xt[c + 0][r] = v.x; Xt[c + 1][r] = v.y;
            Xt[c + 2][r] = v.z; Xt[c + 3][r] = v.w;
        }
    }
    // stage W tile (128 k x 64 cols)
    {
        const int k  = t >> 1;
        const int c0 = (t & 1) * 32;
        const float* src = W + k * 128 + col0 + c0;
#pragma unroll
        for (int j = 0; j < 8; ++j)
            *(float4*)&Ws[k][c0 + j * 4] = *(const float4*)(src + j * 4);
    }
    __syncthreads();

    const int tx = t & 15;   // col group
    const int ty = t >> 4;   // row group
    float acc[4][4];
#pragma unroll
    for (int i = 0; i < 4; ++i)
#pragma unroll
        for (int j = 0; j < 4; ++j) acc[i][j] = 0.f;

#pragma unroll 8
    for (int k = 0; k < 128; ++k) {
        const float4 a = *(const float4*)&Xt[k][ty * 4];
        const float4 b = *(const float4*)&Ws[k][tx * 4];
        acc[0][0] += a.x * b.x; acc[0][1] += a.x * b.y; acc[0][2] += a.x * b.z; acc[0][3] += a.x * b.w;
        acc[1][0] += a.y * b.x; acc[1][1] += a.y * b.y; acc[1][2] += a.y * b.z; acc[1][3] += a.y * b.w;
        acc[2][0] += a.z * b.x; acc[2][1] += a.z * b.y; acc[2][2] += a.z * b.z; acc[2][3] += a.z * b.w;
        acc[3][0] += a.w * b.x; acc[3][1] += a.w * b.y; acc[3][2] += a.w * b.z; acc[3][3] += a.w * b.w;
    }

#pragma unroll
    for (int i = 0; i < 4; ++i) {
        const int row = row0 + ty * 4 + i;
        if (row < N) {
            float4 o = make_float4(acc[i][0], acc[i][1], acc[i][2], acc[i][3]);
            *(float4*)&C[(size_t)row * 128 + col0 + tx * 4] = o;
        }
    }
}

// ---------------- edge scatter: agg[dst] += t[src] * dinv[src]*dinv[dst] ----------------
// one wave per edge; lane f handles features f and f+64
__global__ __launch_bounds__(256) void k_scatter(const int* __restrict__ src,
                                                 const int* __restrict__ dst, int E,
                                                 const float* __restrict__ t,
                                                 const float* __restrict__ dinv,
                                                 float* __restrict__ agg) {
    const int e = blockIdx.x * 4 + (threadIdx.x >> 6);
    if (e >= E) return;
    const int lane = threadIdx.x & 63;
    const int s = src[e];
    const int d = dst[e];
    const float coef = dinv[s] * dinv[d];
    const float* tr = t + (size_t)s * 128;
    float* ar = agg + (size_t)d * 128;
    atomicAdd(&ar[lane],      tr[lane]      * coef);
    atomicAdd(&ar[lane + 64], tr[lane + 64] * coef);
}

// ---------------- finalize: out = agg + t*dinv^2 (self loop) + bias, optional relu ----------------
__global__ __launch_bounds__(256) void k_finalize(const float* __restrict__ agg,
                                                  const float* __restrict__ t,
                                                  const float* __restrict__ dinv,
                                                  const float* __restrict__ bias,
                                                  float* __restrict__ out,
                                                  int N, int relu) {
    const int i = blockIdx.x * 256 + threadIdx.x;
    const int base = i * 4;
    if (base >= N * 128) return;
    const int v = base >> 7;
    const int f = base & 127;
    const float s = dinv[v] * dinv[v];
    float4 a  = *(const float4*)&agg[base];
    float4 tv = *(const float4*)&t[base];
    float4 b  = *(const float4*)&bias[f];
    float4 o;
    o.x = a.x + tv.x * s + b.x;
    o.y = a.y + tv.y * s + b.y;
    o.z = a.z + tv.z * s + b.z;
    o.w = a.w + tv.w * s + b.w;
    if (relu) {
        o.x = fmaxf(o.x, 0.f); o.y = fmaxf(o.y, 0.f);
        o.z = fmaxf(o.z, 0.f); o.w = fmaxf(o.w, 0.f);
    }
    *(float4*)&out[base] = o;
}

extern "C" void kernel_launch(void* const* d_in, const int* in_sizes, int n_in,
                              void* d_out, int out_size, void* d_ws, size_t ws_size,
                              hipStream_t stream) {
    const float* x   = (const float*)d_in[0];
    const int*   ei  = (const int*)d_in[1];   // int32 on device (harness converts integer inputs)
    const float* W1  = (const float*)d_in[2];
    const float* b1  = (const float*)d_in[3];
    const float* W2  = (const float*)d_in[4];
    const float* b2  = (const float*)d_in[5];
    float*       out = (float*)d_out;

    const int N = in_sizes[0] / 128;
    const int E = in_sizes[1] / 2;
    const int* esrc = ei;
    const int* edst = ei + E;
    const size_t NF = (size_t)N * 128;

    // workspace layout (~52 MB): deg, dinv, one N x 128 scratch
    char* ws = (char*)d_ws;
    size_t o = 0;
    float* deg  = (float*)(ws + o); o += (size_t)N * 4;  o = (o + 255) & ~(size_t)255;
    float* dinv = (float*)(ws + o); o += (size_t)N * 4;  o = (o + 255) & ~(size_t)255;
    float* t    = (float*)(ws + o); o += NF * 4;

    hipMemsetAsync(deg, 0, (size_t)N * 4, stream);
    hipMemsetAsync(out, 0, NF * 4, stream);

    k_deg <<<idiv_up(E, 256), 256, 0, stream>>>(edst, E, deg);
    k_dinv<<<idiv_up(N, 256), 256, 0, stream>>>(deg, dinv, N);

    dim3 ggrid(idiv_up(N, 64), 2);

    // ---- layer 1 : h = relu(Ahat * (x@W1) + b1), h lives in d_out ----
    k_gemm    <<<ggrid, 256, 0, stream>>>(x, W1, t, N);
    k_scatter <<<idiv_up(E, 4), 256, 0, stream>>>(esrc, edst, E, t, dinv, out);
    k_finalize<<<idiv_up(N * 32, 256), 256, 0, stream>>>(out, t, dinv, b1, out, N, 1);

    // ---- layer 2 : out = Ahat * (h@W2) + b2 ----
    k_gemm    <<<ggrid, 256, 0, stream>>>(out, W2, t, N);   // t2 = h @ W2
    hipMemsetAsync(out, 0, NF * 4, stream);                 // h dead; reuse d_out as agg2
    k_scatter <<<idiv_up(E, 4), 256, 0, stream>>>(esrc, edst, E, t, dinv, out);
    k_finalize<<<idiv_up(N * 32, 256), 256, 0, stream>>>(out, t, dinv, b2, out, N, 0);
}

// Round 3
// 572.870 us; speedup vs baseline: 2.7652x; 2.7652x over previous
//
#include <hip/hip_runtime.h>

static inline int idiv_up(int a, int b) { return (a + b - 1) / b; }

// ---------------- histogram of dst (in-degree, excluding self loop) ----------------
__global__ __launch_bounds__(256) void k_hist(const int* __restrict__ dst, int E,
                                              int* __restrict__ cnt) {
    int i = blockIdx.x * 256 + threadIdx.x;
    if (i < E) atomicAdd(&cnt[dst[i]], 1);
}

__global__ __launch_bounds__(256) void k_dinv(const int* __restrict__ cnt,
                                              float* __restrict__ dinv, int N) {
    int i = blockIdx.x * 256 + threadIdx.x;
    if (i < N) dinv[i] = rsqrtf((float)cnt[i] + 1.0f);  // +1 = self loop
}

// ---------------- exclusive scan over cnt[N] -> rowptr[N+1] ----------------
__global__ __launch_bounds__(256) void k_scan1(const int* __restrict__ cnt, int N,
                                               int* __restrict__ rowptr,
                                               int* __restrict__ partials) {
    __shared__ int s[256];
    const int tid = threadIdx.x;
    const int i = blockIdx.x * 256 + tid;
    const int v = (i < N) ? cnt[i] : 0;
    s[tid] = v;
    __syncthreads();
#pragma unroll
    for (int off = 1; off < 256; off <<= 1) {
        int x = 0;
        if (tid >= off) x = s[tid - off];
        __syncthreads();
        if (tid >= off) s[tid] += x;
        __syncthreads();
    }
    if (i < N) rowptr[i] = s[tid] - v;           // exclusive within block
    if (tid == 255) partials[blockIdx.x] = s[255];
}

__global__ void k_scan2(int* __restrict__ partials, int nb,
                        int* __restrict__ rowptr, int N) {
    if (threadIdx.x == 0 && blockIdx.x == 0) {
        int run = 0;
        for (int b = 0; b < nb; ++b) { int v = partials[b]; partials[b] = run; run += v; }
        rowptr[N] = run;  // == E
    }
}

__global__ __launch_bounds__(256) void k_scan3(int* __restrict__ rowptr, int N,
                                               const int* __restrict__ partials) {
    int i = blockIdx.x * 256 + threadIdx.x;
    if (i < N) rowptr[i] += partials[blockIdx.x];
}

// ---------------- CSR fill: csr[pos] = (src, coef) ----------------
__global__ __launch_bounds__(256) void k_fill(const int* __restrict__ src,
                                              const int* __restrict__ dst, int E,
                                              const int* __restrict__ rowptr,
                                              int* __restrict__ cursor,
                                              const float* __restrict__ dinv,
                                              int2* __restrict__ csr) {
    int e = blockIdx.x * 256 + threadIdx.x;
    if (e >= E) return;
    const int s = src[e];
    const int d = dst[e];
    const int pos = rowptr[d] + atomicAdd(&cursor[d], 1);
    csr[pos] = make_int2(s, __float_as_int(dinv[s] * dinv[d]));
}

// ---------------- fp32 GEMM: C[N,128] = A[N,128] @ W[128,128] ----------------
// 64x64 tile per block, 256 threads, 4x4 outputs per thread.
__global__ __launch_bounds__(256) void k_gemm(const float* __restrict__ A,
                                              const float* __restrict__ W,
                                              float* __restrict__ C, int N) {
    __shared__ float Xt[128][64];  // A tile transposed: Xt[k][r]
    __shared__ float Ws[128][64];  // W tile: Ws[k][c]
    const int t = threadIdx.x;
    const int row0 = blockIdx.x * 64;
    const int col0 = blockIdx.y * 64;

    {
        const int r  = t >> 2;
        const int c0 = (t & 3) * 32;
        const int row = row0 + r;
        const float* src = A + (size_t)row * 128 + c0;
#pragma unroll
        for (int j = 0; j < 8; ++j) {
            float4 v = make_float4(0.f, 0.f, 0.f, 0.f);
            if (row < N) v = *(const float4*)(src + j * 4);
            const int c = c0 + j * 4;
            Xt[c + 0][r] = v.x; Xt[c + 1][r] = v.y;
            Xt[c + 2][r] = v.z; Xt[c + 3][r] = v.w;
        }
    }
    {
        const int k  = t >> 1;
        const int c0 = (t & 1) * 32;
        const float* src = W + k * 128 + col0 + c0;
#pragma unroll
        for (int j = 0; j < 8; ++j)
            *(float4*)&Ws[k][c0 + j * 4] = *(const float4*)(src + j * 4);
    }
    __syncthreads();

    const int tx = t & 15;
    const int ty = t >> 4;
    float acc[4][4];
#pragma unroll
    for (int i = 0; i < 4; ++i)
#pragma unroll
        for (int j = 0; j < 4; ++j) acc[i][j] = 0.f;

#pragma unroll 8
    for (int k = 0; k < 128; ++k) {
        const float4 a = *(const float4*)&Xt[k][ty * 4];
        const float4 b = *(const float4*)&Ws[k][tx * 4];
        acc[0][0] += a.x * b.x; acc[0][1] += a.x * b.y; acc[0][2] += a.x * b.z; acc[0][3] += a.x * b.w;
        acc[1][0] += a.y * b.x; acc[1][1] += a.y * b.y; acc[1][2] += a.y * b.z; acc[1][3] += a.y * b.w;
        acc[2][0] += a.z * b.x; acc[2][1] += a.z * b.y; acc[2][2] += a.z * b.z; acc[2][3] += a.z * b.w;
        acc[3][0] += a.w * b.x; acc[3][1] += a.w * b.y; acc[3][2] += a.w * b.z; acc[3][3] += a.w * b.w;
    }

#pragma unroll
    for (int i = 0; i < 4; ++i) {
        const int row = row0 + ty * 4 + i;
        if (row < N) {
            float4 o = make_float4(acc[i][0], acc[i][1], acc[i][2], acc[i][3]);
            *(float4*)&C[(size_t)row * 128 + col0 + tx * 4] = o;
        }
    }
}

// ---------------- fused pull aggregation + self-loop + bias (+relu) ----------------
// one wave per dst node; lane f handles features f and f+64
__global__ __launch_bounds__(256) void k_pull(const int* __restrict__ rowptr,
                                              const int2* __restrict__ csr,
                                              const float* __restrict__ t,
                                              const float* __restrict__ dinv,
                                              const float* __restrict__ bias,
                                              float* __restrict__ out,
                                              int N, int relu) {
    const int nid = blockIdx.x * 4 + (threadIdx.x >> 6);
    if (nid >= N) return;
    const int lane = threadIdx.x & 63;
    const int beg = rowptr[nid];
    const int end = rowptr[nid + 1];

    float acc0 = 0.f, acc1 = 0.f;
    int2 e = (beg < end) ? csr[beg] : make_int2(0, 0);
    for (int j = beg; j < end; ++j) {
        int2 nxt = (j + 1 < end) ? csr[j + 1] : make_int2(0, 0);  // prefetch
        const float w = __int_as_float(e.y);
        const float* tr = t + (size_t)e.x * 128;
        acc0 += tr[lane] * w;
        acc1 += tr[lane + 64] * w;
        e = nxt;
    }
    // self loop
    const float ds = dinv[nid];
    const float ws = ds * ds;
    const float* tr = t + (size_t)nid * 128;
    acc0 += tr[lane] * ws + bias[lane];
    acc1 += tr[lane + 64] * ws + bias[lane + 64];
    if (relu) { acc0 = fmaxf(acc0, 0.f); acc1 = fmaxf(acc1, 0.f); }
    float* orow = out + (size_t)nid * 128;
    orow[lane]      = acc0;
    orow[lane + 64] = acc1;
}

extern "C" void kernel_launch(void* const* d_in, const int* in_sizes, int n_in,
                              void* d_out, int out_size, void* d_ws, size_t ws_size,
                              hipStream_t stream) {
    const float* x   = (const float*)d_in[0];
    const int*   ei  = (const int*)d_in[1];
    const float* W1  = (const float*)d_in[2];
    const float* b1  = (const float*)d_in[3];
    const float* W2  = (const float*)d_in[4];
    const float* b2  = (const float*)d_in[5];
    float*       out = (float*)d_out;

    const int N = in_sizes[0] / 128;
    const int E = in_sizes[1] / 2;
    const int* esrc = ei;
    const int* edst = ei + E;
    const size_t NF = (size_t)N * 128;
    const int nb = idiv_up(N, 256);

    // workspace layout: cnt[N], rowptr[N+1], cursor[N], partials[nb], dinv[N],
    //                   t[N*128], csr[E] (int2)   ≈ 71 MB
    char* ws = (char*)d_ws;
    size_t o = 0;
    int*   cnt      = (int*)(ws + o); o += (size_t)N * 4;        o = (o + 255) & ~(size_t)255;
    int*   rowptr   = (int*)(ws + o); o += ((size_t)N + 1) * 4;  o = (o + 255) & ~(size_t)255;
    int*   cursor   = (int*)(ws + o); o += (size_t)N * 4;        o = (o + 255) & ~(size_t)255;
    int*   partials = (int*)(ws + o); o += (size_t)nb * 4;       o = (o + 255) & ~(size_t)255;
    float* dinv     = (float*)(ws + o); o += (size_t)N * 4;      o = (o + 255) & ~(size_t)255;
    float* t        = (float*)(ws + o); o += NF * 4;             o = (o + 255) & ~(size_t)255;
    int2*  csr      = (int2*)(ws + o); o += (size_t)E * 8;

    hipMemsetAsync(cnt, 0, (size_t)N * 4, stream);
    hipMemsetAsync(cursor, 0, (size_t)N * 4, stream);

    // ---- CSR build + norms ----
    k_hist <<<idiv_up(E, 256), 256, 0, stream>>>(edst, E, cnt);
    k_dinv <<<nb, 256, 0, stream>>>(cnt, dinv, N);
    k_scan1<<<nb, 256, 0, stream>>>(cnt, N, rowptr, partials);
    k_scan2<<<1, 64, 0, stream>>>(partials, nb, rowptr, N);
    k_scan3<<<nb, 256, 0, stream>>>(rowptr, N, partials);
    k_fill <<<idiv_up(E, 256), 256, 0, stream>>>(esrc, edst, E, rowptr, cursor, dinv, csr);

    dim3 ggrid(idiv_up(N, 64), 2);

    // ---- layer 1 : h = relu(Ahat * (x@W1) + b1), h lives in d_out ----
    k_gemm<<<ggrid, 256, 0, stream>>>(x, W1, t, N);
    k_pull<<<idiv_up(N, 4), 256, 0, stream>>>(rowptr, csr, t, dinv, b1, out, N, 1);

    // ---- layer 2 : out = Ahat * (h@W2) + b2 ----
    k_gemm<<<ggrid, 256, 0, stream>>>(out, W2, t, N);
    k_pull<<<idiv_up(N, 4), 256, 0, stream>>>(rowptr, csr, t, dinv, b2, out, N, 0);
}

// Round 5
// 538.798 us; speedup vs baseline: 2.9401x; 1.0632x over previous
//
#include <hip/hip_runtime.h>

static inline int idiv_up(int a, int b) { return (a + b - 1) / b; }

__device__ __forceinline__ float bf16u_to_f32(unsigned short u) {
    return __uint_as_float(((unsigned int)u) << 16);
}

__device__ __forceinline__ unsigned short f32_to_bf16u(float x) {
    unsigned int b = __float_as_uint(x);
    b += 0x7FFFu + ((b >> 16) & 1u);   // round-to-nearest-even
    return (unsigned short)(b >> 16);
}

// ---------------- histogram of dst (in-degree, excluding self loop) ----------------
__global__ __launch_bounds__(256) void k_hist(const int* __restrict__ dst, int E,
                                              int* __restrict__ cnt) {
    int i = blockIdx.x * 256 + threadIdx.x;
    if (i < E) atomicAdd(&cnt[dst[i]], 1);
}

__global__ __launch_bounds__(256) void k_dinv(const int* __restrict__ cnt,
                                              float* __restrict__ dinv, int N) {
    int i = blockIdx.x * 256 + threadIdx.x;
    if (i < N) dinv[i] = rsqrtf((float)cnt[i] + 1.0f);  // +1 = self loop
}

// ---------------- exclusive scan over cnt[N] -> rowptr[N+1] ----------------
__global__ __launch_bounds__(256) void k_scan1(const int* __restrict__ cnt, int N,
                                               int* __restrict__ rowptr,
                                               int* __restrict__ partials) {
    __shared__ int s[256];
    const int tid = threadIdx.x;
    const int i = blockIdx.x * 256 + tid;
    const int v = (i < N) ? cnt[i] : 0;
    s[tid] = v;
    __syncthreads();
#pragma unroll
    for (int off = 1; off < 256; off <<= 1) {
        int x = 0;
        if (tid >= off) x = s[tid - off];
        __syncthreads();
        if (tid >= off) s[tid] += x;
        __syncthreads();
    }
    if (i < N) rowptr[i] = s[tid] - v;           // exclusive within block
    if (tid == 255) partials[blockIdx.x] = s[255];
}

__global__ void k_scan2(int* __restrict__ partials, int nb,
                        int* __restrict__ rowptr, int N) {
    if (threadIdx.x == 0 && blockIdx.x == 0) {
        int run = 0;
        for (int b = 0; b < nb; ++b) { int v = partials[b]; partials[b] = run; run += v; }
        rowptr[N] = run;  // == E
    }
}

__global__ __launch_bounds__(256) void k_scan3(int* __restrict__ rowptr, int N,
                                               const int* __restrict__ partials) {
    int i = blockIdx.x * 256 + threadIdx.x;
    if (i < N) rowptr[i] += partials[blockIdx.x];
}

// ---------------- CSR fill: csr[pos] = (src, coef); consumes cnt via atomicSub ----------------
__global__ __launch_bounds__(256) void k_fill(const int* __restrict__ src,
                                              const int* __restrict__ dst, int E,
                                              const int* __restrict__ rowptr,
                                              int* __restrict__ cnt,
                                              const float* __restrict__ dinv,
                                              int2* __restrict__ csr) {
    int e = blockIdx.x * 256 + threadIdx.x;
    if (e >= E) return;
    const int s = src[e];
    const int d = dst[e];
    const int pos = rowptr[d] + atomicSub(&cnt[d], 1) - 1;
    csr[pos] = make_int2(s, __float_as_int(dinv[s] * dinv[d]));
}

// ---------------- fp32 GEMM: C[N,128] = A[N,128] @ W[128,128], bf16 output ----------------
// 64x64 tile per block, 256 threads, 4x4 outputs per thread.
__global__ __launch_bounds__(256) void k_gemm(const float* __restrict__ A,
                                              const float* __restrict__ W,
                                              unsigned short* __restrict__ C, int N) {
    __shared__ float Xt[128][64];  // A tile transposed: Xt[k][r]
    __shared__ float Ws[128][64];  // W tile: Ws[k][c]
    const int t = threadIdx.x;
    const int row0 = blockIdx.x * 64;
    const int col0 = blockIdx.y * 64;

    {
        const int r  = t >> 2;
        const int c0 = (t & 3) * 32;
        const int row = row0 + r;
        const float* src = A + (size_t)row * 128 + c0;
#pragma unroll
        for (int j = 0; j < 8; ++j) {
            float4 v = make_float4(0.f, 0.f, 0.f, 0.f);
            if (row < N) v = *(const float4*)(src + j * 4);
            const int c = c0 + j * 4;
            Xt[c + 0][r] = v.x; Xt[c + 1][r] = v.y;
            Xt[c + 2][r] = v.z; Xt[c + 3][r] = v.w;
        }
    }
    {
        const int k  = t >> 1;
        const int c0 = (t & 1) * 32;
        const float* src = W + k * 128 + col0 + c0;
#pragma unroll
        for (int j = 0; j < 8; ++j)
            *(float4*)&Ws[k][c0 + j * 4] = *(const float4*)(src + j * 4);
    }
    __syncthreads();

    const int tx = t & 15;
    const int ty = t >> 4;
    float acc[4][4];
#pragma unroll
    for (int i = 0; i < 4; ++i)
#pragma unroll
        for (int j = 0; j < 4; ++j) acc[i][j] = 0.f;

#pragma unroll 8
    for (int k = 0; k < 128; ++k) {
        const float4 a = *(const float4*)&Xt[k][ty * 4];
        const float4 b = *(const float4*)&Ws[k][tx * 4];
        acc[0][0] += a.x * b.x; acc[0][1] += a.x * b.y; acc[0][2] += a.x * b.z; acc[0][3] += a.x * b.w;
        acc[1][0] += a.y * b.x; acc[1][1] += a.y * b.y; acc[1][2] += a.y * b.z; acc[1][3] += a.y * b.w;
        acc[2][0] += a.z * b.x; acc[2][1] += a.z * b.y; acc[2][2] += a.z * b.z; acc[2][3] += a.z * b.w;
        acc[3][0] += a.w * b.x; acc[3][1] += a.w * b.y; acc[3][2] += a.w * b.z; acc[3][3] += a.w * b.w;
    }

#pragma unroll
    for (int i = 0; i < 4; ++i) {
        const int row = row0 + ty * 4 + i;
        if (row < N) {
            ushort4 o;
            o.x = f32_to_bf16u(acc[i][0]);
            o.y = f32_to_bf16u(acc[i][1]);
            o.z = f32_to_bf16u(acc[i][2]);
            o.w = f32_to_bf16u(acc[i][3]);
            *(ushort4*)&C[(size_t)row * 128 + col0 + tx * 4] = o;
        }
    }
}

// ---------------- fused pull aggregation + self-loop + bias (+relu) ----------------
// one wave per dst node; lane handles features 2*lane and 2*lane+1 (bf16 gather)
__global__ __launch_bounds__(256) void k_pull(const int* __restrict__ rowptr,
                                              const int2* __restrict__ csr,
                                              const unsigned short* __restrict__ t,
                                              const float* __restrict__ dinv,
                                              const float* __restrict__ bias,
                                              float* __restrict__ out,
                                              int N, int relu) {
    const int nid = blockIdx.x * 4 + (threadIdx.x >> 6);
    if (nid >= N) return;
    const int lane = threadIdx.x & 63;
    const int beg = rowptr[nid];
    const int end = rowptr[nid + 1];

    float acc0 = 0.f, acc1 = 0.f;
    int2 e = (beg < end) ? csr[beg] : make_int2(0, 0);
    for (int j = beg; j < end; ++j) {
        int2 nxt = (j + 1 < end) ? csr[j + 1] : make_int2(0, 0);  // prefetch
        const float w = __int_as_float(e.y);
        const ushort2 u = *(const ushort2*)(t + (size_t)e.x * 128 + lane * 2);
        acc0 += bf16u_to_f32(u.x) * w;
        acc1 += bf16u_to_f32(u.y) * w;
        e = nxt;
    }
    // self loop
    const float ds = dinv[nid];
    const float wsl = ds * ds;
    const ushort2 us = *(const ushort2*)(t + (size_t)nid * 128 + lane * 2);
    const float2 b = *(const float2*)(bias + lane * 2);
    acc0 += bf16u_to_f32(us.x) * wsl + b.x;
    acc1 += bf16u_to_f32(us.y) * wsl + b.y;
    if (relu) { acc0 = fmaxf(acc0, 0.f); acc1 = fmaxf(acc1, 0.f); }
    *(float2*)(out + (size_t)nid * 128 + lane * 2) = make_float2(acc0, acc1);
}

extern "C" void kernel_launch(void* const* d_in, const int* in_sizes, int n_in,
                              void* d_out, int out_size, void* d_ws, size_t ws_size,
                              hipStream_t stream) {
    const float* x   = (const float*)d_in[0];
    const int*   ei  = (const int*)d_in[1];
    const float* W1  = (const float*)d_in[2];
    const float* b1  = (const float*)d_in[3];
    const float* W2  = (const float*)d_in[4];
    const float* b2  = (const float*)d_in[5];
    float*       out = (float*)d_out;

    const int N = in_sizes[0] / 128;
    const int E = in_sizes[1] / 2;
    const int* esrc = ei;
    const int* edst = ei + E;
    const size_t NF = (size_t)N * 128;
    const int nb = idiv_up(N, 256);

    // workspace: cnt[N], rowptr[N+1], partials[nb], dinv[N], t bf16[N*128], csr int2[E]  ≈ 40 MB
    char* ws = (char*)d_ws;
    size_t o = 0;
    int*            cnt      = (int*)(ws + o);   o += (size_t)N * 4;       o = (o + 255) & ~(size_t)255;
    int*            rowptr   = (int*)(ws + o);   o += ((size_t)N + 1) * 4; o = (o + 255) & ~(size_t)255;
    int*            partials = (int*)(ws + o);   o += (size_t)nb * 4;      o = (o + 255) & ~(size_t)255;
    float*          dinv     = (float*)(ws + o); o += (size_t)N * 4;       o = (o + 255) & ~(size_t)255;
    unsigned short* t        = (unsigned short*)(ws + o); o += NF * 2;     o = (o + 255) & ~(size_t)255;
    int2*           csr      = (int2*)(ws + o);  o += (size_t)E * 8;

    hipMemsetAsync(cnt, 0, (size_t)N * 4, stream);

    // ---- CSR build + norms ----
    k_hist <<<idiv_up(E, 256), 256, 0, stream>>>(edst, E, cnt);
    k_dinv <<<nb, 256, 0, stream>>>(cnt, dinv, N);
    k_scan1<<<nb, 256, 0, stream>>>(cnt, N, rowptr, partials);
    k_scan2<<<1, 64, 0, stream>>>(partials, nb, rowptr, N);
    k_scan3<<<nb, 256, 0, stream>>>(rowptr, N, partials);
    k_fill <<<idiv_up(E, 256), 256, 0, stream>>>(esrc, edst, E, rowptr, cnt, dinv, csr);

    dim3 ggrid(idiv_up(N, 64), 2);

    // ---- layer 1 : h = relu(Ahat * (x@W1) + b1), h lives in d_out (fp32) ----
    k_gemm<<<ggrid, 256, 0, stream>>>(x, W1, t, N);
    k_pull<<<idiv_up(N, 4), 256, 0, stream>>>(rowptr, csr, t, dinv, b1, out, N, 1);

    // ---- layer 2 : out = Ahat * (h@W2) + b2 ----
    k_gemm<<<ggrid, 256, 0, stream>>>(out, W2, t, N);
    k_pull<<<idiv_up(N, 4), 256, 0, stream>>>(rowptr, csr, t, dinv, b2, out, N, 0);
}

// Round 6
// 465.012 us; speedup vs baseline: 3.4066x; 1.1587x over previous
//
#include <hip/hip_runtime.h>

static inline int idiv_up(int a, int b) { return (a + b - 1) / b; }

__device__ __forceinline__ float bf16u_to_f32(unsigned short u) {
    return __uint_as_float(((unsigned int)u) << 16);
}

__device__ __forceinline__ unsigned short f32_to_bf16u(float x) {
    unsigned int b = __float_as_uint(x);
    b += 0x7FFFu + ((b >> 16) & 1u);   // round-to-nearest-even
    return (unsigned short)(b >> 16);
}

// ---------------- histogram of dst (in-degree, excluding self loop) ----------------
__global__ __launch_bounds__(256) void k_hist(const int* __restrict__ dst, int E,
                                              int* __restrict__ cnt) {
    int i = blockIdx.x * 256 + threadIdx.x;
    if (i < E) atomicAdd(&cnt[dst[i]], 1);
}

__global__ __launch_bounds__(256) void k_dinv(const int* __restrict__ cnt,
                                              float* __restrict__ dinv, int N) {
    int i = blockIdx.x * 256 + threadIdx.x;
    if (i < N) dinv[i] = rsqrtf((float)cnt[i] + 1.0f);  // +1 = self loop
}

// ---------------- exclusive scan over cnt[N] -> rowptr[N+1] ----------------
__global__ __launch_bounds__(256) void k_scan1(const int* __restrict__ cnt, int N,
                                               int* __restrict__ rowptr,
                                               int* __restrict__ partials) {
    __shared__ int s[256];
    const int tid = threadIdx.x;
    const int i = blockIdx.x * 256 + tid;
    const int v = (i < N) ? cnt[i] : 0;
    s[tid] = v;
    __syncthreads();
#pragma unroll
    for (int off = 1; off < 256; off <<= 1) {
        int x = 0;
        if (tid >= off) x = s[tid - off];
        __syncthreads();
        if (tid >= off) s[tid] += x;
        __syncthreads();
    }
    if (i < N) rowptr[i] = s[tid] - v;           // exclusive within block
    if (tid == 255) partials[blockIdx.x] = s[255];
}

__global__ void k_scan2(int* __restrict__ partials, int nb,
                        int* __restrict__ rowptr, int N) {
    if (threadIdx.x == 0 && blockIdx.x == 0) {
        int run = 0;
        for (int b = 0; b < nb; ++b) { int v = partials[b]; partials[b] = run; run += v; }
        rowptr[N] = run;  // == E
    }
}

__global__ __launch_bounds__(256) void k_scan3(int* __restrict__ rowptr, int N,
                                               const int* __restrict__ partials) {
    int i = blockIdx.x * 256 + threadIdx.x;
    if (i < N) rowptr[i] += partials[blockIdx.x];
}

// ---------------- CSR fill: csr[pos] = (src, coef); consumes cnt via atomicSub ----------------
__global__ __launch_bounds__(256) void k_fill(const int* __restrict__ src,
                                              const int* __restrict__ dst, int E,
                                              const int* __restrict__ rowptr,
                                              int* __restrict__ cnt,
                                              const float* __restrict__ dinv,
                                              int2* __restrict__ csr) {
    int e = blockIdx.x * 256 + threadIdx.x;
    if (e >= E) return;
    const int s = src[e];
    const int d = dst[e];
    const int pos = rowptr[d] + atomicSub(&cnt[d], 1) - 1;
    csr[pos] = make_int2(s, __float_as_int(dinv[s] * dinv[d]));
}

// ---------------- fp32 GEMM: C[N,128] = A[N,128] @ W[128,128], bf16 output ----------------
// 64x64 tile per block, 256 threads, 4x4 outputs per thread.
__global__ __launch_bounds__(256) void k_gemm(const float* __restrict__ A,
                                              const float* __restrict__ W,
                                              unsigned short* __restrict__ C, int N) {
    __shared__ float Xt[128][64];  // A tile transposed: Xt[k][r]
    __shared__ float Ws[128][64];  // W tile: Ws[k][c]
    const int t = threadIdx.x;
    const int row0 = blockIdx.x * 64;
    const int col0 = blockIdx.y * 64;

    {
        const int r  = t >> 2;
        const int c0 = (t & 3) * 32;
        const int row = row0 + r;
        const float* src = A + (size_t)row * 128 + c0;
#pragma unroll
        for (int j = 0; j < 8; ++j) {
            float4 v = make_float4(0.f, 0.f, 0.f, 0.f);
            if (row < N) v = *(const float4*)(src + j * 4);
            const int c = c0 + j * 4;
            Xt[c + 0][r] = v.x; Xt[c + 1][r] = v.y;
            Xt[c + 2][r] = v.z; Xt[c + 3][r] = v.w;
        }
    }
    {
        const int k  = t >> 1;
        const int c0 = (t & 1) * 32;
        const float* src = W + k * 128 + col0 + c0;
#pragma unroll
        for (int j = 0; j < 8; ++j)
            *(float4*)&Ws[k][c0 + j * 4] = *(const float4*)(src + j * 4);
    }
    __syncthreads();

    const int tx = t & 15;
    const int ty = t >> 4;
    float acc[4][4];
#pragma unroll
    for (int i = 0; i < 4; ++i)
#pragma unroll
        for (int j = 0; j < 4; ++j) acc[i][j] = 0.f;

#pragma unroll 8
    for (int k = 0; k < 128; ++k) {
        const float4 a = *(const float4*)&Xt[k][ty * 4];
        const float4 b = *(const float4*)&Ws[k][tx * 4];
        acc[0][0] += a.x * b.x; acc[0][1] += a.x * b.y; acc[0][2] += a.x * b.z; acc[0][3] += a.x * b.w;
        acc[1][0] += a.y * b.x; acc[1][1] += a.y * b.y; acc[1][2] += a.y * b.z; acc[1][3] += a.y * b.w;
        acc[2][0] += a.z * b.x; acc[2][1] += a.z * b.y; acc[2][2] += a.z * b.z; acc[2][3] += a.z * b.w;
        acc[3][0] += a.w * b.x; acc[3][1] += a.w * b.y; acc[3][2] += a.w * b.z; acc[3][3] += a.w * b.w;
    }

#pragma unroll
    for (int i = 0; i < 4; ++i) {
        const int row = row0 + ty * 4 + i;
        if (row < N) {
            ushort4 o;
            o.x = f32_to_bf16u(acc[i][0]);
            o.y = f32_to_bf16u(acc[i][1]);
            o.z = f32_to_bf16u(acc[i][2]);
            o.w = f32_to_bf16u(acc[i][3]);
            *(ushort4*)&C[(size_t)row * 128 + col0 + tx * 4] = o;
        }
    }
}

// ---------------- fused pull aggregation + self-loop + bias (+relu) ----------------
// one wave per dst node; lane handles features 2*lane, 2*lane+1 (bf16 gather).
// Edge loop unrolled x4: 4 independent gathers in flight per wave (MLP).
__global__ __launch_bounds__(256) void k_pull(const int* __restrict__ rowptr,
                                              const int2* __restrict__ csr,
                                              const unsigned short* __restrict__ t,
                                              const float* __restrict__ dinv,
                                              const float* __restrict__ bias,
                                              float* __restrict__ out,
                                              int N, int relu) {
    const int nid = blockIdx.x * 4 + (threadIdx.x >> 6);
    if (nid >= N) return;
    const int lane2 = (threadIdx.x & 63) * 2;
    const int beg = rowptr[nid];
    const int end = rowptr[nid + 1];

    float acc0 = 0.f, acc1 = 0.f;
    int j = beg;
    for (; j + 4 <= end; j += 4) {
        const int2 e0 = csr[j];
        const int2 e1 = csr[j + 1];
        const int2 e2 = csr[j + 2];
        const int2 e3 = csr[j + 3];
        const ushort2 u0 = *(const ushort2*)(t + (size_t)e0.x * 128 + lane2);
        const ushort2 u1 = *(const ushort2*)(t + (size_t)e1.x * 128 + lane2);
        const ushort2 u2 = *(const ushort2*)(t + (size_t)e2.x * 128 + lane2);
        const ushort2 u3 = *(const ushort2*)(t + (size_t)e3.x * 128 + lane2);
        const float w0 = __int_as_float(e0.y);
        const float w1 = __int_as_float(e1.y);
        const float w2 = __int_as_float(e2.y);
        const float w3 = __int_as_float(e3.y);
        acc0 += bf16u_to_f32(u0.x) * w0; acc1 += bf16u_to_f32(u0.y) * w0;
        acc0 += bf16u_to_f32(u1.x) * w1; acc1 += bf16u_to_f32(u1.y) * w1;
        acc0 += bf16u_to_f32(u2.x) * w2; acc1 += bf16u_to_f32(u2.y) * w2;
        acc0 += bf16u_to_f32(u3.x) * w3; acc1 += bf16u_to_f32(u3.y) * w3;
    }
    for (; j < end; ++j) {
        const int2 e = csr[j];
        const float w = __int_as_float(e.y);
        const ushort2 u = *(const ushort2*)(t + (size_t)e.x * 128 + lane2);
        acc0 += bf16u_to_f32(u.x) * w;
        acc1 += bf16u_to_f32(u.y) * w;
    }
    // self loop
    const float ds = dinv[nid];
    const float wsl = ds * ds;
    const ushort2 us = *(const ushort2*)(t + (size_t)nid * 128 + lane2);
    const float2 b = *(const float2*)(bias + lane2);
    acc0 += bf16u_to_f32(us.x) * wsl + b.x;
    acc1 += bf16u_to_f32(us.y) * wsl + b.y;
    if (relu) { acc0 = fmaxf(acc0, 0.f); acc1 = fmaxf(acc1, 0.f); }
    *(float2*)(out + (size_t)nid * 128 + lane2) = make_float2(acc0, acc1);
}

extern "C" void kernel_launch(void* const* d_in, const int* in_sizes, int n_in,
                              void* d_out, int out_size, void* d_ws, size_t ws_size,
                              hipStream_t stream) {
    const float* x   = (const float*)d_in[0];
    const int*   ei  = (const int*)d_in[1];
    const float* W1  = (const float*)d_in[2];
    const float* b1  = (const float*)d_in[3];
    const float* W2  = (const float*)d_in[4];
    const float* b2  = (const float*)d_in[5];
    float*       out = (float*)d_out;

    const int N = in_sizes[0] / 128;
    const int E = in_sizes[1] / 2;
    const int* esrc = ei;
    const int* edst = ei + E;
    const size_t NF = (size_t)N * 128;
    const int nb = idiv_up(N, 256);

    // workspace: cnt[N], rowptr[N+1], partials[nb], dinv[N], t bf16[N*128], csr int2[E]  ≈ 40 MB
    char* ws = (char*)d_ws;
    size_t o = 0;
    int*            cnt      = (int*)(ws + o);   o += (size_t)N * 4;       o = (o + 255) & ~(size_t)255;
    int*            rowptr   = (int*)(ws + o);   o += ((size_t)N + 1) * 4; o = (o + 255) & ~(size_t)255;
    int*            partials = (int*)(ws + o);   o += (size_t)nb * 4;      o = (o + 255) & ~(size_t)255;
    float*          dinv     = (float*)(ws + o); o += (size_t)N * 4;       o = (o + 255) & ~(size_t)255;
    unsigned short* t        = (unsigned short*)(ws + o); o += NF * 2;     o = (o + 255) & ~(size_t)255;
    int2*           csr      = (int2*)(ws + o);  o += (size_t)E * 8;

    hipMemsetAsync(cnt, 0, (size_t)N * 4, stream);

    // ---- CSR build + norms ----
    k_hist <<<idiv_up(E, 256), 256, 0, stream>>>(edst, E, cnt);
    k_dinv <<<nb, 256, 0, stream>>>(cnt, dinv, N);
    k_scan1<<<nb, 256, 0, stream>>>(cnt, N, rowptr, partials);
    k_scan2<<<1, 64, 0, stream>>>(partials, nb, rowptr, N);
    k_scan3<<<nb, 256, 0, stream>>>(rowptr, N, partials);
    k_fill <<<idiv_up(E, 256), 256, 0, stream>>>(esrc, edst, E, rowptr, cnt, dinv, csr);

    dim3 ggrid(idiv_up(N, 64), 2);

    // ---- layer 1 : h = relu(Ahat * (x@W1) + b1), h lives in d_out (fp32) ----
    k_gemm<<<ggrid, 256, 0, stream>>>(x, W1, t, N);
    k_pull<<<idiv_up(N, 4), 256, 0, stream>>>(rowptr, csr, t, dinv, b1, out, N, 1);

    // ---- layer 2 : out = Ahat * (h@W2) + b2 ----
    k_gemm<<<ggrid, 256, 0, stream>>>(out, W2, t, N);
    k_pull<<<idiv_up(N, 4), 256, 0, stream>>>(rowptr, csr, t, dinv, b2, out, N, 0);
}

// Round 7
// 388.138 us; speedup vs baseline: 4.0813x; 1.1981x over previous
//
#include <hip/hip_runtime.h>

static inline int idiv_up(int a, int b) { return (a + b - 1) / b; }

typedef __attribute__((ext_vector_type(8))) short bf16x8;
typedef __attribute__((ext_vector_type(4))) float f32x4;

__device__ __forceinline__ float bf16u_to_f32(unsigned short u) {
    return __uint_as_float(((unsigned int)u) << 16);
}

__device__ __forceinline__ unsigned short f32_to_bf16u(float x) {
    unsigned int b = __float_as_uint(x);
    b += 0x7FFFu + ((b >> 16) & 1u);   // round-to-nearest-even
    return (unsigned short)(b >> 16);
}

// ---------------- histogram of dst (in-degree, excluding self loop) ----------------
__global__ __launch_bounds__(256) void k_hist(const int* __restrict__ dst, int E,
                                              int* __restrict__ cnt) {
    int i = blockIdx.x * 256 + threadIdx.x;
    if (i < E) atomicAdd(&cnt[dst[i]], 1);
}

__global__ __launch_bounds__(256) void k_dinv(const int* __restrict__ cnt,
                                              float* __restrict__ dinv, int N) {
    int i = blockIdx.x * 256 + threadIdx.x;
    if (i < N) dinv[i] = rsqrtf((float)cnt[i] + 1.0f);  // +1 = self loop
}

// ---------------- exclusive scan over cnt[N] -> rowptr[N+1] ----------------
__global__ __launch_bounds__(256) void k_scan1(const int* __restrict__ cnt, int N,
                                               int* __restrict__ rowptr,
                                               int* __restrict__ partials) {
    __shared__ int s[256];
    const int tid = threadIdx.x;
    const int i = blockIdx.x * 256 + tid;
    const int v = (i < N) ? cnt[i] : 0;
    s[tid] = v;
    __syncthreads();
#pragma unroll
    for (int off = 1; off < 256; off <<= 1) {
        int x = 0;
        if (tid >= off) x = s[tid - off];
        __syncthreads();
        if (tid >= off) s[tid] += x;
        __syncthreads();
    }
    if (i < N) rowptr[i] = s[tid] - v;           // exclusive within block
    if (tid == 255) partials[blockIdx.x] = s[255];
}

__global__ void k_scan2(int* __restrict__ partials, int nb,
                        int* __restrict__ rowptr, int N) {
    if (threadIdx.x == 0 && blockIdx.x == 0) {
        int run = 0;
        for (int b = 0; b < nb; ++b) { int v = partials[b]; partials[b] = run; run += v; }
        rowptr[N] = run;  // == E
    }
}

__global__ __launch_bounds__(256) void k_scan3(int* __restrict__ rowptr, int N,
                                               const int* __restrict__ partials) {
    int i = blockIdx.x * 256 + threadIdx.x;
    if (i < N) rowptr[i] += partials[blockIdx.x];
}

// ---------------- CSR fill: csr[pos] = (src, coef); consumes cnt via atomicSub ----------------
__global__ __launch_bounds__(256) void k_fill(const int* __restrict__ src,
                                              const int* __restrict__ dst, int E,
                                              const int* __restrict__ rowptr,
                                              int* __restrict__ cnt,
                                              const float* __restrict__ dinv,
                                              int2* __restrict__ csr) {
    int e = blockIdx.x * 256 + threadIdx.x;
    if (e >= E) return;
    const int s = src[e];
    const int d = dst[e];
    const int pos = rowptr[d] + atomicSub(&cnt[d], 1) - 1;
    csr[pos] = make_int2(s, __float_as_int(dinv[s] * dinv[d]));
}

// ---------------- bf16 MFMA GEMM: C[N,128] = A[N,128] @ W[128,128], bf16 out ----------------
// 256 threads = 4 waves; block tile 128 rows x 128 cols, K = 128.
// Per wave: rows [32w,32w+32) as 2 row-tiles x 8 col-tiles of 16x16, 4 K-steps of 32.
// A-frags loaded directly from global fp32 (each row consumed by exactly one wave).
// W staged once per block to LDS transposed (Wt[col][k], bf16, XOR-swizzled).
__global__ __launch_bounds__(256) void k_gemm(const float* __restrict__ A,
                                              const float* __restrict__ W,
                                              unsigned short* __restrict__ C, int N) {
    __shared__ unsigned short Wt[128 * 128];   // 32 KB
    const int tid = threadIdx.x;

    // ---- stage Wt[col][k] = bf16(W[k][col]), swizzle: kus ^ ((col&7)<<3) ----
    {
        const int col = tid >> 1;
        const int k0  = (tid & 1) * 64;
#pragma unroll
        for (int i = 0; i < 8; ++i) {
            bf16x8 pk;
#pragma unroll
            for (int j = 0; j < 8; ++j)
                pk[j] = (short)f32_to_bf16u(W[(size_t)(k0 + i * 8 + j) * 128 + col]);
            const int kus = k0 + i * 8;
            *(bf16x8*)&Wt[col * 128 + (kus ^ ((col & 7) << 3))] = pk;
        }
    }
    __syncthreads();

    const int wave = tid >> 6;
    const int lane = tid & 63;
    const int lrow = lane & 15;
    const int lgrp = lane >> 4;
    const int rbase = blockIdx.x * 128 + wave * 32;

    f32x4 acc[2][8];
#pragma unroll
    for (int r = 0; r < 2; ++r)
#pragma unroll
        for (int c = 0; c < 8; ++c) acc[r][c] = (f32x4){0.f, 0.f, 0.f, 0.f};

#pragma unroll
    for (int kk = 0; kk < 4; ++kk) {
        const int kbase = kk * 32 + lgrp * 8;
        // A fragments: row = rbase + r*16 + lrow, k = kbase..kbase+7 (contiguous)
        bf16x8 afrag[2];
#pragma unroll
        for (int r = 0; r < 2; ++r) {
            const int row = rbase + r * 16 + lrow;
            float4 f0 = make_float4(0.f, 0.f, 0.f, 0.f);
            float4 f1 = make_float4(0.f, 0.f, 0.f, 0.f);
            if (row < N) {
                const float* p = A + (size_t)row * 128 + kbase;
                f0 = *(const float4*)p;
                f1 = *(const float4*)(p + 4);
            }
            bf16x8 a;
            a[0] = (short)f32_to_bf16u(f0.x); a[1] = (short)f32_to_bf16u(f0.y);
            a[2] = (short)f32_to_bf16u(f0.z); a[3] = (short)f32_to_bf16u(f0.w);
            a[4] = (short)f32_to_bf16u(f1.x); a[5] = (short)f32_to_bf16u(f1.y);
            a[6] = (short)f32_to_bf16u(f1.z); a[7] = (short)f32_to_bf16u(f1.w);
            afrag[r] = a;
        }
        // B fragments from LDS + 16 MFMA
#pragma unroll
        for (int c = 0; c < 8; ++c) {
            const int col = c * 16 + lrow;
            const bf16x8 b = *(const bf16x8*)&Wt[col * 128 + (kbase ^ ((col & 7) << 3))];
            acc[0][c] = __builtin_amdgcn_mfma_f32_16x16x32_bf16(afrag[0], b, acc[0][c], 0, 0, 0);
            acc[1][c] = __builtin_amdgcn_mfma_f32_16x16x32_bf16(afrag[1], b, acc[1][c], 0, 0, 0);
        }
    }

    // ---- epilogue: C/D layout col = lane&15, row = (lane>>4)*4 + reg ----
#pragma unroll
    for (int r = 0; r < 2; ++r) {
#pragma unroll
        for (int reg = 0; reg < 4; ++reg) {
            const int orow = rbase + r * 16 + lgrp * 4 + reg;
            if (orow < N) {
                unsigned short* crow = C + (size_t)orow * 128 + lrow;
#pragma unroll
                for (int c = 0; c < 8; ++c)
                    crow[c * 16] = f32_to_bf16u(acc[r][c][reg]);
            }
        }
    }
}

// ---------------- fused pull aggregation + self-loop + bias (+relu) ----------------
// one wave per dst node; lane handles features 2*lane, 2*lane+1 (bf16 gather).
// Edge loop unrolled x4: 4 independent gathers in flight per wave (MLP).
__global__ __launch_bounds__(256) void k_pull(const int* __restrict__ rowptr,
                                              const int2* __restrict__ csr,
                                              const unsigned short* __restrict__ t,
                                              const float* __restrict__ dinv,
                                              const float* __restrict__ bias,
                                              float* __restrict__ out,
                                              int N, int relu) {
    const int nid = blockIdx.x * 4 + (threadIdx.x >> 6);
    if (nid >= N) return;
    const int lane2 = (threadIdx.x & 63) * 2;
    const int beg = rowptr[nid];
    const int end = rowptr[nid + 1];

    float acc0 = 0.f, acc1 = 0.f;
    int j = beg;
    for (; j + 4 <= end; j += 4) {
        const int2 e0 = csr[j];
        const int2 e1 = csr[j + 1];
        const int2 e2 = csr[j + 2];
        const int2 e3 = csr[j + 3];
        const ushort2 u0 = *(const ushort2*)(t + (size_t)e0.x * 128 + lane2);
        const ushort2 u1 = *(const ushort2*)(t + (size_t)e1.x * 128 + lane2);
        const ushort2 u2 = *(const ushort2*)(t + (size_t)e2.x * 128 + lane2);
        const ushort2 u3 = *(const ushort2*)(t + (size_t)e3.x * 128 + lane2);
        const float w0 = __int_as_float(e0.y);
        const float w1 = __int_as_float(e1.y);
        const float w2 = __int_as_float(e2.y);
        const float w3 = __int_as_float(e3.y);
        acc0 += bf16u_to_f32(u0.x) * w0; acc1 += bf16u_to_f32(u0.y) * w0;
        acc0 += bf16u_to_f32(u1.x) * w1; acc1 += bf16u_to_f32(u1.y) * w1;
        acc0 += bf16u_to_f32(u2.x) * w2; acc1 += bf16u_to_f32(u2.y) * w2;
        acc0 += bf16u_to_f32(u3.x) * w3; acc1 += bf16u_to_f32(u3.y) * w3;
    }
    for (; j < end; ++j) {
        const int2 e = csr[j];
        const float w = __int_as_float(e.y);
        const ushort2 u = *(const ushort2*)(t + (size_t)e.x * 128 + lane2);
        acc0 += bf16u_to_f32(u.x) * w;
        acc1 += bf16u_to_f32(u.y) * w;
    }
    // self loop
    const float ds = dinv[nid];
    const float wsl = ds * ds;
    const ushort2 us = *(const ushort2*)(t + (size_t)nid * 128 + lane2);
    const float2 b = *(const float2*)(bias + lane2);
    acc0 += bf16u_to_f32(us.x) * wsl + b.x;
    acc1 += bf16u_to_f32(us.y) * wsl + b.y;
    if (relu) { acc0 = fmaxf(acc0, 0.f); acc1 = fmaxf(acc1, 0.f); }
    *(float2*)(out + (size_t)nid * 128 + lane2) = make_float2(acc0, acc1);
}

extern "C" void kernel_launch(void* const* d_in, const int* in_sizes, int n_in,
                              void* d_out, int out_size, void* d_ws, size_t ws_size,
                              hipStream_t stream) {
    const float* x   = (const float*)d_in[0];
    const int*   ei  = (const int*)d_in[1];
    const float* W1  = (const float*)d_in[2];
    const float* b1  = (const float*)d_in[3];
    const float* W2  = (const float*)d_in[4];
    const float* b2  = (const float*)d_in[5];
    float*       out = (float*)d_out;

    const int N = in_sizes[0] / 128;
    const int E = in_sizes[1] / 2;
    const int* esrc = ei;
    const int* edst = ei + E;
    const size_t NF = (size_t)N * 128;
    const int nb = idiv_up(N, 256);

    // workspace: cnt[N], rowptr[N+1], partials[nb], dinv[N], t bf16[N*128], csr int2[E]  ≈ 40 MB
    char* ws = (char*)d_ws;
    size_t o = 0;
    int*            cnt      = (int*)(ws + o);   o += (size_t)N * 4;       o = (o + 255) & ~(size_t)255;
    int*            rowptr   = (int*)(ws + o);   o += ((size_t)N + 1) * 4; o = (o + 255) & ~(size_t)255;
    int*            partials = (int*)(ws + o);   o += (size_t)nb * 4;      o = (o + 255) & ~(size_t)255;
    float*          dinv     = (float*)(ws + o); o += (size_t)N * 4;       o = (o + 255) & ~(size_t)255;
    unsigned short* t        = (unsigned short*)(ws + o); o += NF * 2;     o = (o + 255) & ~(size_t)255;
    int2*           csr      = (int2*)(ws + o);  o += (size_t)E * 8;

    hipMemsetAsync(cnt, 0, (size_t)N * 4, stream);

    // ---- CSR build + norms ----
    k_hist <<<idiv_up(E, 256), 256, 0, stream>>>(edst, E, cnt);
    k_dinv <<<nb, 256, 0, stream>>>(cnt, dinv, N);
    k_scan1<<<nb, 256, 0, stream>>>(cnt, N, rowptr, partials);
    k_scan2<<<1, 64, 0, stream>>>(partials, nb, rowptr, N);
    k_scan3<<<nb, 256, 0, stream>>>(rowptr, N, partials);
    k_fill <<<idiv_up(E, 256), 256, 0, stream>>>(esrc, edst, E, rowptr, cnt, dinv, csr);

    const int gblocks = idiv_up(N, 128);

    // ---- layer 1 : h = relu(Ahat * (x@W1) + b1), h lives in d_out (fp32) ----
    k_gemm<<<gblocks, 256, 0, stream>>>(x, W1, t, N);
    k_pull<<<idiv_up(N, 4), 256, 0, stream>>>(rowptr, csr, t, dinv, b1, out, N, 1);

    // ---- layer 2 : out = Ahat * (h@W2) + b2 ----
    k_gemm<<<gblocks, 256, 0, stream>>>(out, W2, t, N);
    k_pull<<<idiv_up(N, 4), 256, 0, stream>>>(rowptr, csr, t, dinv, b2, out, N, 0);
}